// Round 5
// baseline (223.607 us; speedup 1.0000x reference)
//
#include <hip/hip_runtime.h>
#include <hip/hip_bf16.h>

#define T_STEPS 128
#define D_IN    300
#define H_DIM   100
#define KDIM    400            // D + H
#define KSTRIDE 424            // padded k stride in ushorts (848B rows)
#define WAVES   8
#define BLOCK   (WAVES * 64)   // 512
#define MROWS   16             // batch rows per block
#define NRES    3              // resident W tiles per wave (8*3=24; tile 24 via LDS on wave 7)
#define LN2E    1.44269504f
#define LN2E2   2.88539008f

typedef __attribute__((ext_vector_type(8))) short bf16x8;
typedef __attribute__((ext_vector_type(4))) float f32x4;

__device__ __forceinline__ ushort f2bf(float f) {
    uint u = __float_as_uint(f);
    u += 0x7FFFu + ((u >> 16) & 1u);     // RNE (prepass only)
    return (ushort)(u >> 16);
}
__device__ __forceinline__ uint cvt_pk_bf16(float lo, float hi) {
    uint r;
    asm("v_cvt_pk_bf16_f32 %0, %1, %2" : "=v"(r) : "v"(lo), "v"(hi));
    return r;
}
// Opaque 16B global load: cannot be rematerialized/sunk -> forces VGPR residency.
__device__ __forceinline__ bf16x8 gload16(const ushort* p) {
    bf16x8 r;
    asm volatile("global_load_dwordx4 %0, %1, off" : "=v"(r) : "v"(p));
    return r;
}

// Gate math, division-free. z pre-scaled by log2(e) (2*log2(e) for j),
// biases (incl. forget bias) folded into acc init. Updates c, returns h.
__device__ __forceinline__ float lstm_gate(const f32x4 z, float& c) {
    float ei = __builtin_amdgcn_exp2f(-z[0]);
    float ej = __builtin_amdgcn_exp2f(fminf(-z[1], 126.0f));
    float ef = __builtin_amdgcn_exp2f(-z[2]);
    float eo = __builtin_amdgcn_exp2f(-z[3]);
    float rf  = __builtin_amdgcn_rcpf(1.0f + ef);
    float rij = __builtin_amdgcn_rcpf((1.0f + ei) * (1.0f + ej));
    float c2 = c * rf + (1.0f - ej) * rij;
    c = c2;
    float ec = __builtin_amdgcn_exp2f(fminf(-LN2E2 * c2, 126.0f));
    return (1.0f - ec) * __builtin_amdgcn_rcpf((1.0f + ec) * (1.0f + eo));
}

// ---- Prepass: Wt[combo][p][k] bf16, p = 4*unit + gate, [n][k] layout,
// scaled by log2(e) (gate j: 2*log2(e)) ----
__global__ __launch_bounds__(256) void prep_w(
    const float* __restrict__ W0, const float* __restrict__ W1,
    const float* __restrict__ W2, const float* __restrict__ W3,
    ushort* __restrict__ Wt)
{
    int idx = blockIdx.x * 256 + threadIdx.x;
    const int total = 4 * 400 * KSTRIDE;
    if (idx >= total) return;
    int c   = idx / (400 * KSTRIDE);
    int rem = idx - c * (400 * KSTRIDE);
    int p   = rem / KSTRIDE;
    int k   = rem - p * KSTRIDE;
    const float* W = (c == 0) ? W0 : (c == 1) ? W1 : (c == 2) ? W2 : W3;
    const int g = p & 3;
    const float scale = (g == 1) ? LN2E2 : LN2E;
    float v = 0.0f;
    if (k < KDIM) v = W[k * 400 + g * 100 + (p >> 2)] * scale;
    Wt[idx] = f2bf(v);
}

__global__ __launch_bounds__(BLOCK, 2) void lstm_mfma(
    const float* __restrict__ premises,
    const float* __restrict__ hypotheses,
    const float* __restrict__ b0, const float* __restrict__ b1,
    const float* __restrict__ b2, const float* __restrict__ b3,
    const ushort* __restrict__ Wt,
    float* __restrict__ out)
{
    __shared__ ushort xh[2][MROWS * KSTRIDE];   // ping-pong [row][k]
    __shared__ ushort b24[13 * 512];            // tile-24 B frags: [ks][lane] 16B

    const int tid = threadIdx.x;
    const int l   = tid & 63;
    const int w   = tid >> 6;
    const int combo = blockIdx.y;
    const int row0  = blockIdx.x * MROWS;
    const bool backward = (combo & 1) != 0;
    const float* x    = (combo < 2) ? premises : hypotheses;
    const float* bias = (combo == 0) ? b0 : (combo == 1) ? b1 : (combo == 2) ? b2 : b3;
    const ushort* Wc  = Wt + (size_t)combo * 400 * KSTRIDE;

    const int bn = l & 15;            // W-frag row (p within tile)
    const int ul = l >> 4;            // k-chunk on load; unit-within-tile on output

    // ---- resident W fragments (asm loads -> pinned in VGPRs): tiles 3w,3w+1,3w+2 ----
    bf16x8 bfr[NRES][13];
    #pragma unroll
    for (int i = 0; i < NRES; ++i) {
        const ushort* bp = Wc + (size_t)((3 * w + i) * 16 + bn) * KSTRIDE + ul * 8;
        #pragma unroll
        for (int ks = 0; ks < 13; ++ks)
            bfr[i][ks] = gload16(bp + ks * 32);
    }
    asm volatile("s_waitcnt vmcnt(0)" ::: "memory");

    const bool hasS = (w == WAVES - 1);   // wave 7 also handles tile 24 (from LDS)
    if (w == 0) {
        const ushort* bp = Wc + (size_t)(24 * 16 + bn) * KSTRIDE + ul * 8;
        #pragma unroll
        for (int ks = 0; ks < 13; ++ks)
            *reinterpret_cast<bf16x8*>(&b24[ks * 512 + l * 8]) =
                *reinterpret_cast<const bf16x8*>(bp + ks * 32);
    }

    // ---- per-lane bias (acc-init): acc reg j = gate j of unit nt*4+ul ----
    float bv[NRES][4], bvS[4] = {0.f, 0.f, 0.f, 0.f};
    #pragma unroll
    for (int i = 0; i < NRES; ++i) {
        int u = (3 * w + i) * 4 + ul;
        bv[i][0] = LN2E * bias[u];
        bv[i][1] = LN2E2 * bias[100 + u];
        bv[i][2] = LN2E * (bias[200 + u] + 1.0f);
        bv[i][3] = LN2E * bias[300 + u];
    }
    if (hasS) {
        int u = 96 + ul;
        bvS[0] = LN2E * bias[u];
        bvS[1] = LN2E2 * bias[100 + u];
        bvS[2] = LN2E * (bias[200 + u] + 1.0f);
        bvS[3] = LN2E * bias[300 + u];
    }

    // ---- init LDS: zero k-pads (both buffers), zero h of buf0, stage x_0 ----
    for (int i = tid; i < 2 * MROWS * (KSTRIDE - KDIM); i += BLOCK) {
        int b = i / (MROWS * (KSTRIDE - KDIM));
        int j = i - b * (MROWS * (KSTRIDE - KDIM));
        int r = j / (KSTRIDE - KDIM);
        int k = KDIM + (j - r * (KSTRIDE - KDIM));
        xh[b][r * KSTRIDE + k] = 0;
    }
    for (int i = tid; i < MROWS * H_DIM; i += BLOCK) {
        int r = i / H_DIM;
        xh[0][r * KSTRIDE + D_IN + (i - r * H_DIM)] = 0;
    }
    {
        int t0 = backward ? (T_STEPS - 1) : 0;
        for (int c = tid; c < 1200; c += BLOCK) {
            int r = c / 75, cc = c - (c / 75) * 75;
            float4 v = *reinterpret_cast<const float4*>(
                x + ((size_t)(row0 + r) * T_STEPS + t0) * D_IN + cc * 4);
            uint2 q;
            q.x = cvt_pk_bf16(v.x, v.y);
            q.y = cvt_pk_bf16(v.z, v.w);
            *reinterpret_cast<uint2*>(&xh[0][r * KSTRIDE + cc * 4]) = q;
        }
    }
    __syncthreads();

    // lane roles
    const uint a_off = (uint)(l & 15) * KSTRIDE + (uint)(l >> 4) * 8;  // xh-frag read
    const int  row   = l & 15;
    // staging: waves 0-6 only (wave 7 carries tile-24 LDS work)
    const bool stager = (tid < 448);
    const int sc0 = tid, sc1 = tid + 448, sc2 = tid + 896;
    const int sr0 = sc0 / 75, sd0 = sc0 - sr0 * 75;
    const int sr1 = sc1 / 75, sd1 = sc1 - sr1 * 75;
    const int sr2 = sc2 / 75, sd2 = sc2 - sr2 * 75;
    const bool has2 = (sc2 < 1200);

    float creg0 = 0.f, creg1 = 0.f, creg2 = 0.f, cregS = 0.f;

    // 2-deep prefetch register sets
    float4 A0, A1, A2, B0, B1, B2;

    // pre-loop: issue x(step 1) into set A
    if (stager) {
        int tn = backward ? (T_STEPS - 2) : 1;
        A0 = *reinterpret_cast<const float4*>(
            x + ((size_t)(row0 + sr0) * T_STEPS + tn) * D_IN + sd0 * 4);
        A1 = *reinterpret_cast<const float4*>(
            x + ((size_t)(row0 + sr1) * T_STEPS + tn) * D_IN + sd1 * 4);
        if (has2)
            A2 = *reinterpret_cast<const float4*>(
                x + ((size_t)(row0 + sr2) * T_STEPS + tn) * D_IN + sd2 * 4);
    }

    // one timestep; issues x(t+2) into (i0,i1,i2), consumes (u0,u1,u2)=x(t+1)
    auto step = [&](int t, float4& i0, float4& i1, float4& i2,
                           float4& u0, float4& u1, float4& u2) {
        const ushort* cur = &xh[t & 1][0];
        ushort* nxt = &xh[(t & 1) ^ 1][0];

        if (t < T_STEPS - 2 && stager) {
            int tn = backward ? (T_STEPS - 3 - t) : (t + 2);
            i0 = *reinterpret_cast<const float4*>(
                x + ((size_t)(row0 + sr0) * T_STEPS + tn) * D_IN + sd0 * 4);
            i1 = *reinterpret_cast<const float4*>(
                x + ((size_t)(row0 + sr1) * T_STEPS + tn) * D_IN + sd1 * 4);
            if (has2)
                i2 = *reinterpret_cast<const float4*>(
                    x + ((size_t)(row0 + sr2) * T_STEPS + tn) * D_IN + sd2 * 4);
        }

        // ---- MFMA, W-frag as A-operand: acc[j] = gate j of unit nt*4+ul, col = row ----
        f32x4 acc0 = {bv[0][0], bv[0][1], bv[0][2], bv[0][3]};
        f32x4 acc1 = {bv[1][0], bv[1][1], bv[1][2], bv[1][3]};
        f32x4 acc2 = {bv[2][0], bv[2][1], bv[2][2], bv[2][3]};
        f32x4 accS = {bvS[0], bvS[1], bvS[2], bvS[3]};
        #pragma unroll
        for (int ks = 0; ks < 13; ++ks) {
            const bf16x8 a = *reinterpret_cast<const bf16x8*>(cur + a_off + ks * 32);
            acc0 = __builtin_amdgcn_mfma_f32_16x16x32_bf16(bfr[0][ks], a, acc0, 0, 0, 0);
            acc1 = __builtin_amdgcn_mfma_f32_16x16x32_bf16(bfr[1][ks], a, acc1, 0, 0, 0);
            acc2 = __builtin_amdgcn_mfma_f32_16x16x32_bf16(bfr[2][ks], a, acc2, 0, 0, 0);
            if (hasS) {
                const bf16x8 bs = *reinterpret_cast<const bf16x8*>(&b24[ks * 512 + l * 8]);
                accS = __builtin_amdgcn_mfma_f32_16x16x32_bf16(bs, a, accS, 0, 0, 0);
            }
        }

        // ---- gates ----
        float h0 = lstm_gate(acc0, creg0);
        float h1 = lstm_gate(acc1, creg1);
        float h2 = lstm_gate(acc2, creg2);
        uint pk01 = cvt_pk_bf16(h0, h1);
        uint pk2  = cvt_pk_bf16(h2, h2);
        ushort* hdst = nxt + row * KSTRIDE + D_IN + (3 * w) * 4 + ul;
        hdst[0] = (ushort)(pk01 & 0xFFFFu);
        hdst[4] = (ushort)(pk01 >> 16);
        hdst[8] = (ushort)(pk2 & 0xFFFFu);
        if (hasS) {
            float hS = lstm_gate(accS, cregS);
            nxt[row * KSTRIDE + D_IN + 96 + ul] = (ushort)(cvt_pk_bf16(hS, hS) & 0xFFFFu);
        }

        // ---- consume prefetched x(t+1) (loads issued a full step earlier) ----
        if (t < T_STEPS - 1 && stager) {
            uint2 q;
            q.x = cvt_pk_bf16(u0.x, u0.y);
            q.y = cvt_pk_bf16(u0.z, u0.w);
            *reinterpret_cast<uint2*>(&nxt[sr0 * KSTRIDE + sd0 * 4]) = q;
            q.x = cvt_pk_bf16(u1.x, u1.y);
            q.y = cvt_pk_bf16(u1.z, u1.w);
            *reinterpret_cast<uint2*>(&nxt[sr1 * KSTRIDE + sd1 * 4]) = q;
            if (has2) {
                q.x = cvt_pk_bf16(u2.x, u2.y);
                q.y = cvt_pk_bf16(u2.z, u2.w);
                *reinterpret_cast<uint2*>(&nxt[sr2 * KSTRIDE + sd2 * 4]) = q;
            }
        }
        __syncthreads();
    };

    for (int t = 0; t < T_STEPS; t += 2) {
        step(t,     B0, B1, B2, A0, A1, A2);   // even: issue->B, consume A
        step(t + 1, A0, A1, A2, B0, B1, B2);   // odd:  issue->A, consume B
    }

    // ---- final c write ----
    out[(size_t)(row0 + row) * 400 + combo * 100 + (3 * w) * 4 + ul]     = creg0;
    out[(size_t)(row0 + row) * 400 + combo * 100 + (3 * w + 1) * 4 + ul] = creg1;
    out[(size_t)(row0 + row) * 400 + combo * 100 + (3 * w + 2) * 4 + ul] = creg2;
    if (hasS)
        out[(size_t)(row0 + row) * 400 + combo * 100 + 96 + ul] = cregS;
}

extern "C" void kernel_launch(void* const* d_in, const int* in_sizes, int n_in,
                              void* d_out, int out_size, void* d_ws, size_t ws_size,
                              hipStream_t stream) {
    const float* premises   = (const float*)d_in[0];
    const float* hypotheses = (const float*)d_in[1];
    const float* Wp_fw = (const float*)d_in[2];
    const float* bp_fw = (const float*)d_in[3];
    const float* Wp_bw = (const float*)d_in[4];
    const float* bp_bw = (const float*)d_in[5];
    const float* Wh_fw = (const float*)d_in[6];
    const float* bh_fw = (const float*)d_in[7];
    const float* Wh_bw = (const float*)d_in[8];
    const float* bh_bw = (const float*)d_in[9];
    float* out = (float*)d_out;
    ushort* Wt = (ushort*)d_ws;   // 4*400*424*2 = 1.36 MB

    {
        const int total = 4 * 400 * KSTRIDE;
        prep_w<<<(total + 255) / 256, 256, 0, stream>>>(Wp_fw, Wp_bw, Wh_fw, Wh_bw, Wt);
    }
    dim3 grid(1024 / MROWS, 4);
    lstm_mfma<<<grid, dim3(BLOCK), 0, stream>>>(
        premises, hypotheses,
        bp_fw, bp_bw, bh_fw, bh_bw,
        Wt, out);
}